// Round 8
// baseline (185.502 us; speedup 1.0000x reference)
//
#include <hip/hip_runtime.h>
#include <hip/hip_bf16.h>
#include <stdint.h>
#include <math.h>

#define T_SEQ 2048
#define NHEAD 16
#define CDIM 1024
#define QKV2_LD 2048   // packed q/k layout: head h -> q @ h*128, k @ h*128+64

typedef __attribute__((ext_vector_type(8))) short short8;
typedef __attribute__((ext_vector_type(4))) short short4v;
typedef __attribute__((ext_vector_type(4))) float floatx4;
typedef __attribute__((ext_vector_type(2))) unsigned int uint2v;
typedef __attribute__((ext_vector_type(4))) unsigned int uint4v;

static __device__ __forceinline__ short bf16b(float f) {
    __hip_bfloat16 h = __float2bfloat16(f);
    return __builtin_bit_cast(short, h);
}

// ---------------- fused prep: x cast + W transposes (one launch) ----------------
__device__ __forceinline__ void transpose_body(
    const float* __restrict__ in, __hip_bfloat16* __restrict__ out,
    int R, int C, int bx, int by, int tid)
{
    __shared__ short tile[64][65];
    const int r0 = by << 6;
    const int c0 = bx << 6;
    #pragma unroll
    for (int t = 0; t < 4; ++t) {
        int ch = t * 256 + tid;
        int rr = ch >> 4, cc = (ch & 15) << 2;
        float4 v = *(const float4*)(in + (size_t)(r0 + rr) * C + c0 + cc);
        tile[rr][cc + 0] = bf16b(v.x);
        tile[rr][cc + 1] = bf16b(v.y);
        tile[rr][cc + 2] = bf16b(v.z);
        tile[rr][cc + 3] = bf16b(v.w);
    }
    __syncthreads();
    #pragma unroll
    for (int t = 0; t < 2; ++t) {
        int ch = t * 256 + tid;
        int cc = ch >> 3, rr8 = (ch & 7) << 3;
        short8 v;
        #pragma unroll
        for (int j = 0; j < 8; ++j) v[j] = tile[rr8 + j][cc];
        *(short8*)(out + (size_t)(c0 + cc) * R + r0 + rr8) = v;
    }
}

__global__ __launch_bounds__(256) void prep_kernel(
    const float* __restrict__ x,     __hip_bfloat16* __restrict__ xb,
    const float* __restrict__ Wqkv,  __hip_bfloat16* __restrict__ WqkvT,
    const float* __restrict__ Wproj, __hip_bfloat16* __restrict__ WprojT)
{
    const int bid = blockIdx.x;
    const int tid = threadIdx.x;
    if (bid < 2048) {
        int i = (bid * 256 + tid) * 8;
        float4 a = *(const float4*)(x + i);
        float4 b = *(const float4*)(x + i + 4);
        short8 o;
        o[0] = bf16b(a.x); o[1] = bf16b(a.y); o[2] = bf16b(a.z); o[3] = bf16b(a.w);
        o[4] = bf16b(b.x); o[5] = bf16b(b.y); o[6] = bf16b(b.z); o[7] = bf16b(b.w);
        *(short8*)(xb + i) = o;
    } else if (bid < 2816) {
        int r = bid - 2048;
        transpose_body(Wqkv, WqkvT, 1024, 3072, r % 48, r / 48, tid);
    } else {
        int r = bid - 2816;
        transpose_body(Wproj, WprojT, 1024, 1024, r & 15, r >> 4, tid);
    }
}

// ---------------- GEMM (single-buffer, 2-barrier; QKV epilogue w/ LDS-transposed v) ----
// QKV epilogue pre-scales q columns by 1/sqrt(HD)*log2(e) so attn uses exp2 directly.
template <int MI, int NI, int MINW, bool QKV, typename OutT>
__global__ __launch_bounds__(256, MINW) void gemm_bias_kernel(
    const __hip_bfloat16* __restrict__ A,
    const __hip_bfloat16* __restrict__ Bt,
    const float* __restrict__ bias,
    OutT* __restrict__ C,
    __hip_bfloat16* __restrict__ vT,
    int M, int N, int K)
{
    __shared__ short As[MI * 32 * 64];
    __shared__ short Bs[NI * 32 * 64];
    const int tid  = threadIdx.x;
    const int lane = tid & 63;
    const int w    = tid >> 6;
    const int quad = lane >> 4;
    const int c16  = lane & 15;
    const int m0 = blockIdx.x * (MI * 32);
    const int n0 = blockIdx.y * (NI * 32);
    const int wm = (w >> 1) * (MI * 16);
    const int wn = (w & 1) * (NI * 16);

    floatx4 acc[MI][NI] = {};

    for (int kt = 0; kt < K; kt += 64) {
        __syncthreads();
        #pragma unroll
        for (int r = 0; r < MI; ++r) {
            int ch = r * 256 + tid;
            int row = ch >> 3, k8 = (ch & 7) << 3;
            const __hip_bfloat16* ga = A + (size_t)(m0 + row) * K + kt + k8;
            __builtin_amdgcn_global_load_lds(
                (const __attribute__((address_space(1))) void*)ga,
                (__attribute__((address_space(3))) void*)&As[ch * 8], 16, 0, 0);
        }
        #pragma unroll
        for (int r = 0; r < NI; ++r) {
            int ch = r * 256 + tid;
            int row = ch >> 3, k8 = (ch & 7) << 3;
            const __hip_bfloat16* gb = Bt + (size_t)(n0 + row) * K + kt + k8;
            __builtin_amdgcn_global_load_lds(
                (const __attribute__((address_space(1))) void*)gb,
                (__attribute__((address_space(3))) void*)&Bs[ch * 8], 16, 0, 0);
        }
        __syncthreads();
        #pragma unroll
        for (int ko = 0; ko < 64; ko += 32) {
            short8 af[MI], bfr[NI];
            #pragma unroll
            for (int mi = 0; mi < MI; ++mi)
                af[mi] = *(const short8*)&As[(wm + mi * 16 + c16) * 64 + ko + quad * 8];
            #pragma unroll
            for (int ni = 0; ni < NI; ++ni)
                bfr[ni] = *(const short8*)&Bs[(wn + ni * 16 + c16) * 64 + ko + quad * 8];
            #pragma unroll
            for (int mi = 0; mi < MI; ++mi)
                #pragma unroll
                for (int ni = 0; ni < NI; ++ni)
                    acc[mi][ni] = __builtin_amdgcn_mfma_f32_16x16x32_bf16(
                        af[mi], bfr[ni], acc[mi][ni], 0, 0, 0);
        }
    }

    if constexpr (QKV) {
        const int colblk = (n0 + wn) >> 6;
        const int head = colblk / 3;
        const int kind = colblk % 3;
        const int b    = m0 >> 11;
        __syncthreads();
        if (kind == 2) {
            short* tp = (w < 2) ? &As[w * 4096] : &Bs[(w - 2) * 4096];
            #pragma unroll
            for (int mi = 0; mi < MI; ++mi)
                #pragma unroll
                for (int ni = 0; ni < NI; ++ni) {
                    int hd = ni * 16 + c16;
                    float bv = bias[n0 + wn + hd];
                    short4v pk;
                    #pragma unroll
                    for (int r2 = 0; r2 < 4; ++r2) pk[r2] = bf16b(acc[mi][ni][r2] + bv);
                    int tc = mi * 4 + quad;
                    *(short4v*)&tp[hd * 64 + ((tc ^ ((hd & 7) << 1)) << 2)] = pk;
                }
            const size_t vb2 = ((size_t)(b * 16 + head)) * 64 * T_SEQ;
            const int t0 = (m0 + wm) & 2047;
            #pragma unroll
            for (int it = 0; it < 8; ++it) {
                int hd = it * 8 + (lane >> 3);
                int tc2 = (lane & 7) << 1;
                short8 vv = *(const short8*)&tp[hd * 64 + ((tc2 ^ ((hd & 7) << 1)) << 2)];
                *(short8*)(vT + vb2 + (size_t)hd * T_SEQ + t0 + ((lane & 7) << 3)) = vv;
            }
        } else {
            const int cbase = head * 128 + kind * 64;
            // fold softmax scale (1/sqrt(64) * log2(e)) into q so attn uses exp2 directly
            const float qsc = (kind == 0) ? 0.18033688011112042f : 1.0f;
            #pragma unroll
            for (int mi = 0; mi < MI; ++mi)
                #pragma unroll
                for (int ni = 0; ni < NI; ++ni) {
                    float bv = bias[n0 + wn + ni * 16 + c16];
                    int col = cbase + ni * 16 + c16;
                    #pragma unroll
                    for (int r2 = 0; r2 < 4; ++r2) {
                        int row = m0 + wm + mi * 16 + quad * 4 + r2;
                        C[(size_t)row * QKV2_LD + col] =
                            __float2bfloat16((acc[mi][ni][r2] + bv) * qsc);
                    }
                }
        }
    } else {
        #pragma unroll
        for (int mi = 0; mi < MI; ++mi)
            #pragma unroll
            for (int ni = 0; ni < NI; ++ni) {
                int col = n0 + wn + ni * 16 + c16;
                float bv = bias[col];
                #pragma unroll
                for (int r2 = 0; r2 < 4; ++r2) {
                    int row = m0 + wm + mi * 16 + quad * 4 + r2;
                    float v = acc[mi][ni][r2] + bv;
                    if constexpr (__is_same(OutT, float)) {
                        C[(size_t)row * N + col] = v;
                    } else {
                        C[(size_t)row * N + col] = __float2bfloat16(v);
                    }
                }
            }
    }
}

// ---------------- fused causal flash attention (S^T, 32 q-rows per wave) ----------------
// R5 structure (verified correct) with the register budget FIXED: __launch_bounds__(256,2)
// caps at 256 VGPR instead of 128. R5's spill (WRITE 8.2->29 MB) was the 128-cap forcing
// the doubled accumulator state (SA+SB+OA+OB=64 f32) into a bad VGPR/AGPR split; peak
// live here is ~135 regs -> fits under 256 with slack. R7 proved 2 blocks/CU (8 waves/CU)
// saturates per-CU throughput, so the occupancy cost of the 256-cap is zero.
// Each wave: TWO 16-row q-groups (A/B); kf/vb LDS fragments read ONCE feed both groups
// -> per-q LDS reads + staging + barriers halved (LDS-read pipe was ~46% of cycles).
// Grid (32,16)=512 blocks = exactly 2/CU; y-remap pairs {qb,15-qb} co-resident -> every
// CU executes (2qb+2)+(32-2qb) = 34 uniform block-iterations.
__global__ __launch_bounds__(256, 2) void attn_kernel(
    const __hip_bfloat16* __restrict__ qkv,   // [B*T,2048] packed; q(pre-scaled) @ h*128, k @ h*128+64
    const __hip_bfloat16* __restrict__ vT,    // [b*16+h][64][2048]
    __hip_bfloat16* __restrict__ attn_out)    // [B*T,1024]
{
    __shared__ short Ks[2][64 * 64];
    __shared__ short Vs[2][64 * 64];

    const int hb = blockIdx.x;
    const int yj = blockIdx.y & 7, yk = blockIdx.y >> 3;
    const int qb = yk ? (15 - yj) : yj;       // co-resident pair {j,15-j}: equal work
    const int h  = hb & 15;
    const int b  = hb >> 4;
    const int tid  = threadIdx.x;
    const int lane = tid & 63;
    const int w    = tid >> 6;                // 0..3, each wave owns 32 q-rows
    const int quad = lane >> 4;
    const int c16  = lane & 15;

    const size_t rowbase = (size_t)b * T_SEQ;
    const size_t vbase   = (size_t)hb * 64 * T_SEQ;
    const int q0   = qb << 7;                 // 128 q-rows per block
    const int hoff = h * 128;
    const int key  = c16 & 7;
    const int dtw  = (qb << 1) + (w >> 1);    // this wave's diagonal key-tile
    const int lb   = (w & 1) << 5;            // local q base within the diagonal tile
    const int nkt  = (qb << 1) + 2;           // key-tiles staged by the block

    // two q-groups: rows q0 + 32w + 16G + c16
    short8 qf[2][2];                          // [G][ko]
    #pragma unroll
    for (int G = 0; G < 2; ++G)
        #pragma unroll
        for (int ko = 0; ko < 2; ++ko)
            qf[G][ko] = *(const short8*)(qkv +
                (rowbase + q0 + (w << 5) + (G << 4) + c16) * QKV2_LD + hoff + ko * 32 + quad * 8);

    floatx4 OA[4] = {}, OB[4] = {};
    floatx4 lpA = {}, lpB = {};

    auto stage = [&](int kt, int bsel) {
        const int k0s = kt << 6;
        #pragma unroll
        for (int r = 0; r < 2; ++r) {
            int ch = r * 256 + tid;
            int krow = ch >> 3;
            int hc = (ch & 7) ^ (krow & 7);
            const __hip_bfloat16* g = qkv + (rowbase + k0s + krow) * QKV2_LD + hoff + 64 + hc * 8;
            __builtin_amdgcn_global_load_lds(
                (const __attribute__((address_space(1))) void*)g,
                (__attribute__((address_space(3))) void*)&Ks[bsel][ch * 8], 16, 0, 0);
        }
        #pragma unroll
        for (int r = 0; r < 2; ++r) {
            int ch = r * 256 + tid;
            int hd = ch >> 3;
            int kc = (ch & 7) ^ (hd & 7);
            const __hip_bfloat16* g = vT + vbase + (size_t)hd * T_SEQ + k0s + kc * 8;
            __builtin_amdgcn_global_load_lds(
                (const __attribute__((address_space(1))) void*)g,
                (__attribute__((address_space(3))) void*)&Vs[bsel][ch * 8], 16, 0, 0);
        }
    };

    stage(0, 0);
    int buf = 0;

    for (int kt = 0; kt < nkt; ++kt) {
        __syncthreads();
        if (kt + 1 < nkt) stage(kt + 1, buf ^ 1);

        if (kt <= dtw) {   // wave-uniform: waves before their diagonal skip this tile
            // phase 1: per-ko K fragments feed BOTH q-groups; kf dies into QK^T
            floatx4 SA[4] = {}, SB[4] = {};
            #pragma unroll
            for (int ko = 0; ko < 2; ++ko) {
                short8 kf[4];
                #pragma unroll
                for (int ni = 0; ni < 4; ++ni) {
                    int sl = ((4 * ko + quad) ^ key) << 3;
                    kf[ni] = *(const short8*)&Ks[buf][(ni * 16 + c16) * 64 + sl];
                }
                __builtin_amdgcn_s_setprio(1);
                #pragma unroll
                for (int ni = 0; ni < 4; ++ni)
                    SA[ni] = __builtin_amdgcn_mfma_f32_16x16x32_bf16(
                        kf[ni], qf[0][ko], SA[ni], 0, 0, 0);
                #pragma unroll
                for (int ni = 0; ni < 4; ++ni)
                    SB[ni] = __builtin_amdgcn_mfma_f32_16x16x32_bf16(
                        kf[ni], qf[1][ko], SB[ni], 0, 0, 0);
                __builtin_amdgcn_s_setprio(0);
            }

            // phase 2: softmax per group (q pre-scaled by 0.125*log2e -> exp2 directly)
            if (kt == dtw) {
                #pragma unroll
                for (int ni = 0; ni < 4; ++ni)
                    #pragma unroll
                    for (int r = 0; r < 4; ++r) {
                        int keyi = ni * 16 + quad * 4 + r;
                        float pa2 = (keyi > (lb + c16))      ? 0.f : exp2f(SA[ni][r]);
                        float pb2 = (keyi > (lb + 16 + c16)) ? 0.f : exp2f(SB[ni][r]);
                        SA[ni][r] = pa2; lpA[r] += pa2;
                        SB[ni][r] = pb2; lpB[r] += pb2;
                    }
            } else {
                #pragma unroll
                for (int ni = 0; ni < 4; ++ni)
                    #pragma unroll
                    for (int r = 0; r < 4; ++r) {
                        float pa2 = exp2f(SA[ni][r]);
                        float pb2 = exp2f(SB[ni][r]);
                        SA[ni][r] = pa2; lpA[r] += pa2;
                        SB[ni][r] = pb2; lpB[r] += pb2;
                    }
            }

            // phase 3: pack P to bf16 pairs (S dies)
            unsigned pwA[4][2], pwB[4][2];
            #pragma unroll
            for (int ni = 0; ni < 4; ++ni) {
                asm("v_cvt_pk_bf16_f32 %0, %1, %2" : "=v"(pwA[ni][0]) : "v"(SA[ni][0]), "v"(SA[ni][1]));
                asm("v_cvt_pk_bf16_f32 %0, %1, %2" : "=v"(pwA[ni][1]) : "v"(SA[ni][2]), "v"(SA[ni][3]));
                asm("v_cvt_pk_bf16_f32 %0, %1, %2" : "=v"(pwB[ni][0]) : "v"(SB[ni][0]), "v"(SB[ni][1]));
                asm("v_cvt_pk_bf16_f32 %0, %1, %2" : "=v"(pwB[ni][1]) : "v"(SB[ni][2]), "v"(SB[ni][3]));
            }

            // phase 4: per-ko V fragments feed BOTH groups' PV (permlane redistribute)
            #pragma unroll
            for (int ko = 0; ko < 2; ++ko) {
                short8 vb[4];
                #pragma unroll
                for (int ni = 0; ni < 4; ++ni) {
                    int sl = ((4 * ko + quad) ^ key) << 3;
                    vb[ni] = *(const short8*)&Vs[buf][(ni * 16 + c16) * 64 + sl];
                }
                uint4v pbA, pbB;
                {
                    uint2v t0 = __builtin_amdgcn_permlane32_swap(pwA[2 * ko][0], pwA[2 * ko + 1][0], false, false);
                    uint2v u0 = __builtin_amdgcn_permlane16_swap(t0[0], t0[1], false, false);
                    uint2v t1 = __builtin_amdgcn_permlane32_swap(pwA[2 * ko][1], pwA[2 * ko + 1][1], false, false);
                    uint2v u1 = __builtin_amdgcn_permlane16_swap(t1[0], t1[1], false, false);
                    pbA[0] = u0[0]; pbA[2] = u0[1]; pbA[1] = u1[0]; pbA[3] = u1[1];
                }
                {
                    uint2v t0 = __builtin_amdgcn_permlane32_swap(pwB[2 * ko][0], pwB[2 * ko + 1][0], false, false);
                    uint2v u0 = __builtin_amdgcn_permlane16_swap(t0[0], t0[1], false, false);
                    uint2v t1 = __builtin_amdgcn_permlane32_swap(pwB[2 * ko][1], pwB[2 * ko + 1][1], false, false);
                    uint2v u1 = __builtin_amdgcn_permlane16_swap(t1[0], t1[1], false, false);
                    pbB[0] = u0[0]; pbB[2] = u0[1]; pbB[1] = u1[0]; pbB[3] = u1[1];
                }
                short8 paA = __builtin_bit_cast(short8, pbA);
                short8 paB = __builtin_bit_cast(short8, pbB);
                __builtin_amdgcn_s_setprio(1);
                #pragma unroll
                for (int ni = 0; ni < 4; ++ni)
                    OA[ni] = __builtin_amdgcn_mfma_f32_16x16x32_bf16(vb[ni], paA, OA[ni], 0, 0, 0);
                #pragma unroll
                for (int ni = 0; ni < 4; ++ni)
                    OB[ni] = __builtin_amdgcn_mfma_f32_16x16x32_bf16(vb[ni], paB, OB[ni], 0, 0, 0);
                __builtin_amdgcn_s_setprio(0);
            }
        }
        buf ^= 1;
    }

    // epilogue per group: lane-local l, reduce across quads, packed b64 stores
    {
        float l = lpA[0] + lpA[1] + lpA[2] + lpA[3];
        l += __shfl_xor(l, 16);
        l += __shfl_xor(l, 32);
        float inv = 1.0f / l;
        size_t row = rowbase + q0 + (w << 5) + c16;
        #pragma unroll
        for (int ni = 0; ni < 4; ++ni) {
            short4v o;
            #pragma unroll
            for (int r = 0; r < 4; ++r) o[r] = bf16b(OA[ni][r] * inv);
            *(short4v*)(attn_out + row * CDIM + h * 64 + ni * 16 + quad * 4) = o;
        }
    }
    {
        float l = lpB[0] + lpB[1] + lpB[2] + lpB[3];
        l += __shfl_xor(l, 16);
        l += __shfl_xor(l, 32);
        float inv = 1.0f / l;
        size_t row = rowbase + q0 + (w << 5) + 16 + c16;
        #pragma unroll
        for (int ni = 0; ni < 4; ++ni) {
            short4v o;
            #pragma unroll
            for (int r = 0; r < 4; ++r) o[r] = bf16b(OB[ni][r] * inv);
            *(short4v*)(attn_out + row * CDIM + h * 64 + ni * 16 + quad * 4) = o;
        }
    }
}

extern "C" void kernel_launch(void* const* d_in, const int* in_sizes, int n_in,
                              void* d_out, int out_size, void* d_ws, size_t ws_size,
                              hipStream_t stream) {
    const float* x     = (const float*)d_in[0];
    const float* Wqkv  = (const float*)d_in[1];
    const float* bqkv  = (const float*)d_in[2];
    const float* Wproj = (const float*)d_in[3];
    const float* bproj = (const float*)d_in[4];
    float* out = (float*)d_out;

    __hip_bfloat16* xb     = (__hip_bfloat16*)d_ws;
    __hip_bfloat16* WqkvT  = xb     + (size_t)4096 * 1024;
    __hip_bfloat16* WprojT = WqkvT  + (size_t)3072 * 1024;
    __hip_bfloat16* qkv2   = WprojT + (size_t)1024 * 1024;
    __hip_bfloat16* vT     = qkv2   + (size_t)4096 * 2048;
    __hip_bfloat16* attn   = vT     + (size_t)32 * 64 * 2048;

    prep_kernel<<<3072, 256, 0, stream>>>(x, xb, Wqkv, WqkvT, Wproj, WprojT);
    gemm_bias_kernel<4, 4, 2, true, __hip_bfloat16>
        <<<dim3(4096 / 128, 3072 / 128), 256, 0, stream>>>(
        xb, WqkvT, bqkv, qkv2, vT, 4096, 3072, 1024);
    attn_kernel<<<dim3(32, 16), 256, 0, stream>>>(qkv2, vT, attn);
    // proj: 64x128 tile (MI=2,NI=4) -- 16 accs/wave; grid 512 = 2 blocks/CU
    gemm_bias_kernel<2, 4, 2, false, float>
        <<<dim3(4096 / 64, 1024 / 128), 256, 0, stream>>>(
        attn, WprojT, bproj, out, nullptr, 4096, 1024, 1024);
}

// Round 9
// 177.746 us; speedup vs baseline: 1.0436x; 1.0436x over previous
//
#include <hip/hip_runtime.h>
#include <hip/hip_bf16.h>
#include <stdint.h>
#include <math.h>

#define T_SEQ 2048
#define NHEAD 16
#define CDIM 1024
#define QKV2_LD 2048   // packed q/k layout: head h -> q @ h*128, k @ h*128+64

typedef __attribute__((ext_vector_type(8))) short short8;
typedef __attribute__((ext_vector_type(4))) short short4v;
typedef __attribute__((ext_vector_type(4))) float floatx4;
typedef __attribute__((ext_vector_type(2))) unsigned int uint2v;
typedef __attribute__((ext_vector_type(4))) unsigned int uint4v;

static __device__ __forceinline__ short bf16b(float f) {
    __hip_bfloat16 h = __float2bfloat16(f);
    return __builtin_bit_cast(short, h);
}

// ---------------- fused prep: x cast + W transposes (one launch) ----------------
__device__ __forceinline__ void transpose_body(
    const float* __restrict__ in, __hip_bfloat16* __restrict__ out,
    int R, int C, int bx, int by, int tid)
{
    __shared__ short tile[64][65];
    const int r0 = by << 6;
    const int c0 = bx << 6;
    #pragma unroll
    for (int t = 0; t < 4; ++t) {
        int ch = t * 256 + tid;
        int rr = ch >> 4, cc = (ch & 15) << 2;
        float4 v = *(const float4*)(in + (size_t)(r0 + rr) * C + c0 + cc);
        tile[rr][cc + 0] = bf16b(v.x);
        tile[rr][cc + 1] = bf16b(v.y);
        tile[rr][cc + 2] = bf16b(v.z);
        tile[rr][cc + 3] = bf16b(v.w);
    }
    __syncthreads();
    #pragma unroll
    for (int t = 0; t < 2; ++t) {
        int ch = t * 256 + tid;
        int cc = ch >> 3, rr8 = (ch & 7) << 3;
        short8 v;
        #pragma unroll
        for (int j = 0; j < 8; ++j) v[j] = tile[rr8 + j][cc];
        *(short8*)(out + (size_t)(c0 + cc) * R + r0 + rr8) = v;
    }
}

__global__ __launch_bounds__(256) void prep_kernel(
    const float* __restrict__ x,     __hip_bfloat16* __restrict__ xb,
    const float* __restrict__ Wqkv,  __hip_bfloat16* __restrict__ WqkvT,
    const float* __restrict__ Wproj, __hip_bfloat16* __restrict__ WprojT)
{
    const int bid = blockIdx.x;
    const int tid = threadIdx.x;
    if (bid < 2048) {
        int i = (bid * 256 + tid) * 8;
        float4 a = *(const float4*)(x + i);
        float4 b = *(const float4*)(x + i + 4);
        short8 o;
        o[0] = bf16b(a.x); o[1] = bf16b(a.y); o[2] = bf16b(a.z); o[3] = bf16b(a.w);
        o[4] = bf16b(b.x); o[5] = bf16b(b.y); o[6] = bf16b(b.z); o[7] = bf16b(b.w);
        *(short8*)(xb + i) = o;
    } else if (bid < 2816) {
        int r = bid - 2048;
        transpose_body(Wqkv, WqkvT, 1024, 3072, r % 48, r / 48, tid);
    } else {
        int r = bid - 2816;
        transpose_body(Wproj, WprojT, 1024, 1024, r & 15, r >> 4, tid);
    }
}

// ---------------- GEMM (single-buffer, 2-barrier; QKV epilogue w/ LDS-transposed v) ----
// QKV epilogue pre-scales q columns by 1/sqrt(HD)*log2(e) so attn uses exp2 directly.
template <int MI, int NI, int MINW, bool QKV, typename OutT>
__global__ __launch_bounds__(256, MINW) void gemm_bias_kernel(
    const __hip_bfloat16* __restrict__ A,
    const __hip_bfloat16* __restrict__ Bt,
    const float* __restrict__ bias,
    OutT* __restrict__ C,
    __hip_bfloat16* __restrict__ vT,
    int M, int N, int K)
{
    __shared__ short As[MI * 32 * 64];
    __shared__ short Bs[NI * 32 * 64];
    const int tid  = threadIdx.x;
    const int lane = tid & 63;
    const int w    = tid >> 6;
    const int quad = lane >> 4;
    const int c16  = lane & 15;
    const int m0 = blockIdx.x * (MI * 32);
    const int n0 = blockIdx.y * (NI * 32);
    const int wm = (w >> 1) * (MI * 16);
    const int wn = (w & 1) * (NI * 16);

    floatx4 acc[MI][NI] = {};

    for (int kt = 0; kt < K; kt += 64) {
        __syncthreads();
        #pragma unroll
        for (int r = 0; r < MI; ++r) {
            int ch = r * 256 + tid;
            int row = ch >> 3, k8 = (ch & 7) << 3;
            const __hip_bfloat16* ga = A + (size_t)(m0 + row) * K + kt + k8;
            __builtin_amdgcn_global_load_lds(
                (const __attribute__((address_space(1))) void*)ga,
                (__attribute__((address_space(3))) void*)&As[ch * 8], 16, 0, 0);
        }
        #pragma unroll
        for (int r = 0; r < NI; ++r) {
            int ch = r * 256 + tid;
            int row = ch >> 3, k8 = (ch & 7) << 3;
            const __hip_bfloat16* gb = Bt + (size_t)(n0 + row) * K + kt + k8;
            __builtin_amdgcn_global_load_lds(
                (const __attribute__((address_space(1))) void*)gb,
                (__attribute__((address_space(3))) void*)&Bs[ch * 8], 16, 0, 0);
        }
        __syncthreads();
        #pragma unroll
        for (int ko = 0; ko < 64; ko += 32) {
            short8 af[MI], bfr[NI];
            #pragma unroll
            for (int mi = 0; mi < MI; ++mi)
                af[mi] = *(const short8*)&As[(wm + mi * 16 + c16) * 64 + ko + quad * 8];
            #pragma unroll
            for (int ni = 0; ni < NI; ++ni)
                bfr[ni] = *(const short8*)&Bs[(wn + ni * 16 + c16) * 64 + ko + quad * 8];
            #pragma unroll
            for (int mi = 0; mi < MI; ++mi)
                #pragma unroll
                for (int ni = 0; ni < NI; ++ni)
                    acc[mi][ni] = __builtin_amdgcn_mfma_f32_16x16x32_bf16(
                        af[mi], bfr[ni], acc[mi][ni], 0, 0, 0);
        }
    }

    if constexpr (QKV) {
        const int colblk = (n0 + wn) >> 6;
        const int head = colblk / 3;
        const int kind = colblk % 3;
        const int b    = m0 >> 11;
        __syncthreads();
        if (kind == 2) {
            short* tp = (w < 2) ? &As[w * 4096] : &Bs[(w - 2) * 4096];
            #pragma unroll
            for (int mi = 0; mi < MI; ++mi)
                #pragma unroll
                for (int ni = 0; ni < NI; ++ni) {
                    int hd = ni * 16 + c16;
                    float bv = bias[n0 + wn + hd];
                    short4v pk;
                    #pragma unroll
                    for (int r2 = 0; r2 < 4; ++r2) pk[r2] = bf16b(acc[mi][ni][r2] + bv);
                    int tc = mi * 4 + quad;
                    *(short4v*)&tp[hd * 64 + ((tc ^ ((hd & 7) << 1)) << 2)] = pk;
                }
            const size_t vb2 = ((size_t)(b * 16 + head)) * 64 * T_SEQ;
            const int t0 = (m0 + wm) & 2047;
            #pragma unroll
            for (int it = 0; it < 8; ++it) {
                int hd = it * 8 + (lane >> 3);
                int tc2 = (lane & 7) << 1;
                short8 vv = *(const short8*)&tp[hd * 64 + ((tc2 ^ ((hd & 7) << 1)) << 2)];
                *(short8*)(vT + vb2 + (size_t)hd * T_SEQ + t0 + ((lane & 7) << 3)) = vv;
            }
        } else {
            const int cbase = head * 128 + kind * 64;
            // fold softmax scale (1/sqrt(64) * log2(e)) into q so attn uses exp2 directly
            const float qsc = (kind == 0) ? 0.18033688011112042f : 1.0f;
            #pragma unroll
            for (int mi = 0; mi < MI; ++mi)
                #pragma unroll
                for (int ni = 0; ni < NI; ++ni) {
                    float bv = bias[n0 + wn + ni * 16 + c16];
                    int col = cbase + ni * 16 + c16;
                    #pragma unroll
                    for (int r2 = 0; r2 < 4; ++r2) {
                        int row = m0 + wm + mi * 16 + quad * 4 + r2;
                        C[(size_t)row * QKV2_LD + col] =
                            __float2bfloat16((acc[mi][ni][r2] + bv) * qsc);
                    }
                }
        }
    } else {
        #pragma unroll
        for (int mi = 0; mi < MI; ++mi)
            #pragma unroll
            for (int ni = 0; ni < NI; ++ni) {
                int col = n0 + wn + ni * 16 + c16;
                float bv = bias[col];
                #pragma unroll
                for (int r2 = 0; r2 < 4; ++r2) {
                    int row = m0 + wm + mi * 16 + quad * 4 + r2;
                    float v = acc[mi][ni][r2] + bv;
                    if constexpr (__is_same(OutT, float)) {
                        C[(size_t)row * N + col] = v;
                    } else {
                        C[(size_t)row * N + col] = __float2bfloat16(v);
                    }
                }
            }
    }
}

// ---------------- fused causal flash attention (S^T form, in-register P redistribute) --
// FROZEN at the best-measured configuration (R3: 44.4 us, VGPR 60, zero bank conflicts).
// Evidence log: R4 (8-wave QBLK=128) -7%, R5/R8 (32 q/wave) spill at 128-cap / TLP loss
// at (256,2), R7 (uniform pairs, 2/CU) == R3. Conclusion: latency-bound on the per-iter
// chain; 4 ragged blocks/CU with ~13 effective waves is the structure's best point.
// One q-tile of 64 per block; grid (hb=32, 32) = 1024 blocks, 4 blocks/CU (128 KB LDS).
// qt remap: CU-resident groups {j, 15-j, 16+j, 31-j} -> every CU gets 66 work units.
__global__ __launch_bounds__(256, 4) void attn_kernel(
    const __hip_bfloat16* __restrict__ qkv,   // [B*T,2048] packed; q(pre-scaled) @ h*128, k @ h*128+64
    const __hip_bfloat16* __restrict__ vT,    // [b*16+h][64][2048]
    __hip_bfloat16* __restrict__ attn_out)    // [B*T,1024]
{
    __shared__ short Ks[2][64 * 64];
    __shared__ short Vs[2][64 * 64];

    const int hb = blockIdx.x;
    const int yj = blockIdx.y & 7, yk = blockIdx.y >> 3;
    const int qt = (yk & 1) ? ((yk & 2 ? 31 : 15) - yj) : ((yk & 2 ? 16 : 0) + yj);
    const int h  = hb & 15;
    const int b  = hb >> 4;
    const int tid  = threadIdx.x;
    const int lane = tid & 63;
    const int w    = tid >> 6;
    const int quad = lane >> 4;
    const int c16  = lane & 15;

    const size_t rowbase = (size_t)b * T_SEQ;
    const size_t vbase   = (size_t)hb * 64 * T_SEQ;
    const int q0   = qt << 6;
    const int wrow = w << 4;
    const int hoff = h * 128;
    const int key  = c16 & 7;

    short8 qf[2];
    #pragma unroll
    for (int ko = 0; ko < 2; ++ko)
        qf[ko] = *(const short8*)(qkv +
            (rowbase + q0 + wrow + c16) * QKV2_LD + hoff + ko * 32 + quad * 8);

    floatx4 O[4] = {};
    floatx4 lp4 = {};
    const int nkt = qt + 1;

    auto stage = [&](int kt, int bsel) {
        const int k0s = kt << 6;
        #pragma unroll
        for (int r = 0; r < 2; ++r) {
            int ch = r * 256 + tid;
            int krow = ch >> 3;
            int hc = (ch & 7) ^ (krow & 7);
            const __hip_bfloat16* g = qkv + (rowbase + k0s + krow) * QKV2_LD + hoff + 64 + hc * 8;
            __builtin_amdgcn_global_load_lds(
                (const __attribute__((address_space(1))) void*)g,
                (__attribute__((address_space(3))) void*)&Ks[bsel][ch * 8], 16, 0, 0);
        }
        #pragma unroll
        for (int r = 0; r < 2; ++r) {
            int ch = r * 256 + tid;
            int hd = ch >> 3;
            int kc = (ch & 7) ^ (hd & 7);
            const __hip_bfloat16* g = vT + vbase + (size_t)hd * T_SEQ + k0s + kc * 8;
            __builtin_amdgcn_global_load_lds(
                (const __attribute__((address_space(1))) void*)g,
                (__attribute__((address_space(3))) void*)&Vs[bsel][ch * 8], 16, 0, 0);
        }
    };

    stage(0, 0);
    int buf = 0;

    for (int kt = 0; kt < nkt; ++kt) {
        __syncthreads();
        if (kt + 1 < nkt) stage(kt + 1, buf ^ 1);

        // phase 1: K fragments + QK^T (kf dead after)
        short8 kf[2][4];
        #pragma unroll
        for (int ko = 0; ko < 2; ++ko)
            #pragma unroll
            for (int ni = 0; ni < 4; ++ni) {
                int sl = ((4 * ko + quad) ^ key) << 3;
                kf[ko][ni] = *(const short8*)&Ks[buf][(ni * 16 + c16) * 64 + sl];
            }

        floatx4 S[4] = {};
        __builtin_amdgcn_s_setprio(1);
        #pragma unroll
        for (int ko = 0; ko < 2; ++ko)
            #pragma unroll
            for (int ni = 0; ni < 4; ++ni)
                S[ni] = __builtin_amdgcn_mfma_f32_16x16x32_bf16(
                    kf[ko][ni], qf[ko], S[ni], 0, 0, 0);
        __builtin_amdgcn_s_setprio(0);

        // phase 2: issue V fragment loads; latency hides under softmax VALU
        short8 vb[2][4];
        #pragma unroll
        for (int ko = 0; ko < 2; ++ko)
            #pragma unroll
            for (int ni = 0; ni < 4; ++ni) {
                int sl = ((4 * ko + quad) ^ key) << 3;
                vb[ko][ni] = *(const short8*)&Vs[buf][(ni * 16 + c16) * 64 + sl];
            }

        // phase 3: softmax (q pre-scaled by 0.125*log2e -> exp2 directly)
        if (kt == qt) {
            #pragma unroll
            for (int ni = 0; ni < 4; ++ni)
                #pragma unroll
                for (int r = 0; r < 4; ++r) {
                    bool msk = (ni * 16 + quad * 4 + r) > (wrow + c16);
                    float pe = msk ? 0.f : exp2f(S[ni][r]);
                    S[ni][r] = pe;
                    lp4[r] += pe;
                }
        } else {
            #pragma unroll
            for (int ni = 0; ni < 4; ++ni)
                #pragma unroll
                for (int r = 0; r < 4; ++r) {
                    float pe = exp2f(S[ni][r]);
                    S[ni][r] = pe;
                    lp4[r] += pe;
                }
        }

        // phase 4: pack P to bf16 pairs (S dead after)
        // pw[ni][rr] holds keys 16ni+4*quad+2rr,+1 (col = q)
        unsigned pw[4][2];
        #pragma unroll
        for (int ni = 0; ni < 4; ++ni) {
            asm("v_cvt_pk_bf16_f32 %0, %1, %2"
                : "=v"(pw[ni][0]) : "v"(S[ni][0]), "v"(S[ni][1]));
            asm("v_cvt_pk_bf16_f32 %0, %1, %2"
                : "=v"(pw[ni][1]) : "v"(S[ni][2]), "v"(S[ni][3]));
        }

        // phase 5: in-register redistribution to PV B-operand layout (keys 32ko+8*quad+j):
        //   swap32(X=pw[2ko][rr], Y=pw[2ko+1][rr]) -> X'[Q]=pw[2ko+(Q>>1)]@quad(Q&1)
        //   swap16(X', Y')                         -> words 0/2 (rr=0), 1/3 (rr=1)
        #pragma unroll
        for (int ko = 0; ko < 2; ++ko) {
            uint4v pb;
            uint2v t0 = __builtin_amdgcn_permlane32_swap(pw[2 * ko][0], pw[2 * ko + 1][0], false, false);
            uint2v u0 = __builtin_amdgcn_permlane16_swap(t0[0], t0[1], false, false);
            uint2v t1 = __builtin_amdgcn_permlane32_swap(pw[2 * ko][1], pw[2 * ko + 1][1], false, false);
            uint2v u1 = __builtin_amdgcn_permlane16_swap(t1[0], t1[1], false, false);
            pb[0] = u0[0]; pb[2] = u0[1];
            pb[1] = u1[0]; pb[3] = u1[1];
            short8 pa = __builtin_bit_cast(short8, pb);
            __builtin_amdgcn_s_setprio(1);
            #pragma unroll
            for (int ni = 0; ni < 4; ++ni)
                O[ni] = __builtin_amdgcn_mfma_f32_16x16x32_bf16(
                    vb[ko][ni], pa, O[ni], 0, 0, 0);
            __builtin_amdgcn_s_setprio(0);
        }
        buf ^= 1;
    }

    // epilogue: lane-local l, reduce across quads, packed b64 stores
    float l = lp4[0] + lp4[1] + lp4[2] + lp4[3];
    l += __shfl_xor(l, 16);
    l += __shfl_xor(l, 32);
    float inv = 1.0f / l;
    size_t row = rowbase + q0 + wrow + c16;
    #pragma unroll
    for (int ni = 0; ni < 4; ++ni) {
        short4v o;
        #pragma unroll
        for (int r = 0; r < 4; ++r) o[r] = bf16b(O[ni][r] * inv);
        *(short4v*)(attn_out + row * CDIM + h * 64 + ni * 16 + quad * 4) = o;
    }
}

extern "C" void kernel_launch(void* const* d_in, const int* in_sizes, int n_in,
                              void* d_out, int out_size, void* d_ws, size_t ws_size,
                              hipStream_t stream) {
    const float* x     = (const float*)d_in[0];
    const float* Wqkv  = (const float*)d_in[1];
    const float* bqkv  = (const float*)d_in[2];
    const float* Wproj = (const float*)d_in[3];
    const float* bproj = (const float*)d_in[4];
    float* out = (float*)d_out;

    __hip_bfloat16* xb     = (__hip_bfloat16*)d_ws;
    __hip_bfloat16* WqkvT  = xb     + (size_t)4096 * 1024;
    __hip_bfloat16* WprojT = WqkvT  + (size_t)3072 * 1024;
    __hip_bfloat16* qkv2   = WprojT + (size_t)1024 * 1024;
    __hip_bfloat16* vT     = qkv2   + (size_t)4096 * 2048;
    __hip_bfloat16* attn   = vT     + (size_t)32 * 64 * 2048;

    prep_kernel<<<3072, 256, 0, stream>>>(x, xb, Wqkv, WqkvT, Wproj, WprojT);
    gemm_bias_kernel<4, 4, 2, true, __hip_bfloat16>
        <<<dim3(4096 / 128, 3072 / 128), 256, 0, stream>>>(
        xb, WqkvT, bqkv, qkv2, vT, 4096, 3072, 1024);
    attn_kernel<<<dim3(32, 32), 256, 0, stream>>>(qkv2, vT, attn);
    // proj: 64x64 tile <2,2> (R0 best-total config; all proj tilings measured within noise)
    gemm_bias_kernel<2, 2, 4, false, float>
        <<<dim3(4096 / 64, 1024 / 64), 256, 0, stream>>>(
        attn, WprojT, bproj, out, nullptr, 4096, 1024, 1024);
}